// Round 9
// baseline (1828.081 us; speedup 1.0000x reference)
//
#include <hip/hip_runtime.h>
#include <hip/hip_bf16.h>

// Problem constants (from reference)
#define NN 50000
#define EE 800000
#define GG 128
#define LL 4
#define TT 4
#define FF 20
#define DD 80
#define SCAN_B ((NN + 1023) / 1024)   // 49
static constexpr float AVG_LOG = 2.8332133440562162f; // ln(17)

// ---------------- h init: h[n,d] = sum_i atom_emb[i, x[n,i], d] ----------------
__global__ __launch_bounds__(256) void k_h(const int* __restrict__ x,
                                           const float* __restrict__ atom_emb,
                                           float* __restrict__ h) {
  int idx = blockIdx.x * 256 + threadIdx.x;
  if (idx >= NN * DD) return;
  int n = idx / DD, d = idx - n * DD;
  const int* xr = x + n * 9;
  float acc = 0.f;
#pragma unroll
  for (int i = 0; i < 9; ++i) {
    int v = xr[i];
    acc += atom_emb[(i * 16 + v) * DD + d];
  }
  h[idx] = acc;
}

// ---------------- degree count ----------------
__global__ __launch_bounds__(256) void k_deg(const int* __restrict__ ei, int* __restrict__ cnt) {
  int e = blockIdx.x * 256 + threadIdx.x;
  if (e >= EE) return;
  atomicAdd(&cnt[ei[EE + e]], 1); // dst = edge_index[1][e]
}

// ---------------- hierarchical exclusive scan ----------------
__global__ __launch_bounds__(1024) void k_scan_sum(const int* __restrict__ cnt, int* __restrict__ bsum) {
  __shared__ int red[1024];
  int tid = threadIdx.x;
  int i = blockIdx.x * 1024 + tid;
  red[tid] = (i < NN) ? cnt[i] : 0;
  __syncthreads();
  for (int off = 512; off > 0; off >>= 1) {
    if (tid < off) red[tid] += red[tid + off];
    __syncthreads();
  }
  if (tid == 0) bsum[blockIdx.x] = red[0];
}

__global__ void k_scan_top(const int* __restrict__ bsum, int* __restrict__ boff,
                           int* __restrict__ row_ptr) {
  if (threadIdx.x == 0 && blockIdx.x == 0) {
    int acc = 0;
    for (int b = 0; b < SCAN_B; ++b) { boff[b] = acc; acc += bsum[b]; }
    row_ptr[NN] = acc;
  }
}

__global__ __launch_bounds__(1024) void k_scan_apply(const int* __restrict__ cnt,
                                                     const int* __restrict__ boff,
                                                     int* __restrict__ row_ptr,
                                                     int* __restrict__ cursor) {
  __shared__ int sm[1024];
  int tid = threadIdx.x;
  int i = blockIdx.x * 1024 + tid;
  int v = (i < NN) ? cnt[i] : 0;
  sm[tid] = v;
  __syncthreads();
  for (int off = 1; off < 1024; off <<= 1) {
    int t = (tid >= off) ? sm[tid - off] : 0;
    __syncthreads();
    sm[tid] += t;
    __syncthreads();
  }
  int excl = boff[blockIdx.x] + sm[tid] - v;
  if (i < NN) { row_ptr[i] = excl; cursor[i] = excl; }
}

// ---------------- CSR fill: slot -> (src, edge) + dst ----------------
__global__ __launch_bounds__(256) void k_csrfill(const int* __restrict__ ei,
                                                 int* __restrict__ cursor,
                                                 int2* __restrict__ csr2,
                                                 int* __restrict__ csr_dst) {
  int e = blockIdx.x * 256 + threadIdx.x;
  if (e >= EE) return;
  int dst = ei[EE + e];
  int slot = atomicAdd(&cursor[dst], 1);
  csr2[slot] = make_int2(ei[e], e);
  csr_dst[slot] = dst;
}

// ---------------- per-node params ----------------
__global__ __launch_bounds__(256) void k_nodeparams(const int* __restrict__ cnt,
                                                    float* __restrict__ inv_deg,
                                                    float* __restrict__ s1a,
                                                    float* __restrict__ s2a) {
  int n = blockIdx.x * 256 + threadIdx.x;
  if (n >= NN) return;
  int c = cnt[n];
  float deg = (c > 0) ? (float)c : 1.0f;
  inv_deg[n] = 1.0f / deg;
  float logd = logf(deg + 1.0f);
  s1a[n] = logd / AVG_LOG;
  s2a[n] = AVG_LOG / logd;
}

// ---------------- per-layer weight composition ----------------
__global__ __launch_bounds__(64) void k_wcomb(const float* __restrict__ edge_w,
                                              const float* __restrict__ edge_b,
                                              const float* __restrict__ pre_w1,
                                              const float* __restrict__ pre_b1,
                                              float* __restrict__ wc,
                                              float* __restrict__ biasc, int l) {
  int t = blockIdx.x;
  int wt = l * TT + t;
  const float* W1 = pre_w1 + (size_t)wt * 1200; // [60][20]
  const float* ew = edge_w + (size_t)l * 16 * FF;
  const float* eb = edge_b + (size_t)l * FF;
  int j = threadIdx.x;
  if (j >= FF) return;
  for (int i = 0; i < 16; ++i) {
    float acc = 0.f;
#pragma unroll
    for (int f = 0; f < FF; ++f) acc = fmaf(ew[i * FF + f], W1[(40 + f) * FF + j], acc);
    wc[(t * 16 + i) * FF + j] = acc;
  }
  float b = pre_b1[wt * FF + j];
#pragma unroll
  for (int f = 0; f < FF; ++f) b = fmaf(eb[f], W1[(40 + f) * FF + j], b);
  biasc[t * FF + j] = b;
}

// ---------------- per-node pre contributions ----------------
__global__ __launch_bounds__(256) void k_prenode(
    const float* __restrict__ h, const float* __restrict__ pre_w1,
    const float* __restrict__ biasc,
    float* __restrict__ predD, float* __restrict__ predS, int l) {
  int tid = threadIdx.x;
  int t = tid >> 6, lane = tid & 63;
  int n = blockIdx.x * 64 + lane;
  if (n >= NN) return;
  int wt_u = __builtin_amdgcn_readfirstlane(l * TT + t);
  const float* W1 = pre_w1 + (size_t)wt_u * 1200;
  const float* bc = biasc + (tid >> 6) * FF;
  float xt[FF];
  {
    const float4* pp = (const float4*)(h + (size_t)n * DD + t * FF);
#pragma unroll
    for (int i = 0; i < 5; ++i) { float4 v = pp[i]; xt[i*4]=v.x; xt[i*4+1]=v.y; xt[i*4+2]=v.z; xt[i*4+3]=v.w; }
  }
  float d[FF], s[FF];
#pragma unroll
  for (int j = 0; j < FF; ++j) { d[j] = bc[j]; s[j] = 0.f; }
#pragma unroll
  for (int i = 0; i < FF; ++i) {
    float a = xt[i];
#pragma unroll
    for (int j = 0; j < FF; ++j) {
      d[j] = fmaf(a, W1[i * FF + j], d[j]);
      s[j] = fmaf(a, W1[(FF + i) * FF + j], s[j]);
    }
  }
  float4* pd = (float4*)(predD + (size_t)n * DD + t * FF);
  float4* ps = (float4*)(predS + (size_t)n * DD + t * FF);
#pragma unroll
  for (int i = 0; i < 5; ++i) {
    pd[i] = make_float4(d[i*4], d[i*4+1], d[i*4+2], d[i*4+3]);
    ps[i] = make_float4(s[i*4], s[i*4+1], s[i*4+2], s[i*4+3]);
  }
}

// ---------------- edge-parallel pre-MLP (reduced); m channel-major bf16 ----------------
__global__ __launch_bounds__(256, 4) void k_pre(
    const float* __restrict__ predD, const float* __restrict__ predS,
    const float* __restrict__ edge_attr,
    const int2* __restrict__ csr2, const int* __restrict__ csr_dst,
    const int* __restrict__ row_ptr,
    const float* __restrict__ wc,
    const float* __restrict__ pre_w2, const float* __restrict__ pre_b2,
    __hip_bfloat16* __restrict__ m, int l, int n0, int n1, int capSlots) {
  int tid = threadIdx.x;
  int t = tid >> 6;
  int lane = tid & 63;
  int wt_u = __builtin_amdgcn_readfirstlane(l * TT + t);
  int t_u  = __builtin_amdgcn_readfirstlane(t);
  const float* W2 = pre_w2 + (size_t)wt_u * 400;
  const float* b2 = pre_b2 + (size_t)wt_u * FF;
  const float* Wc = wc + (size_t)t_u * 16 * FF;

  int sl = blockIdx.x * 64 + lane;
  int base = row_ptr[n0], end = row_ptr[n1];
  if (sl >= capSlots || base + sl >= end) return;
  int p = base + sl;
  int2 se = csr2[p];
  int dst = csr_dst[p];

  float m1[FF];
  {
    const float4* pp = (const float4*)(predD + (size_t)dst * DD + t * FF);
#pragma unroll
    for (int i = 0; i < 5; ++i) { float4 v = pp[i]; m1[i*4]=v.x; m1[i*4+1]=v.y; m1[i*4+2]=v.z; m1[i*4+3]=v.w; }
  }
  {
    const float4* pp = (const float4*)(predS + (size_t)se.x * DD + t * FF);
#pragma unroll
    for (int i = 0; i < 5; ++i) {
      float4 v = pp[i];
      m1[i*4] += v.x; m1[i*4+1] += v.y; m1[i*4+2] += v.z; m1[i*4+3] += v.w;
    }
  }
  {
    float a[16];
    const float4* ap = (const float4*)(edge_attr + (size_t)se.y * 16);
#pragma unroll
    for (int i = 0; i < 4; ++i) { float4 v = ap[i]; a[i*4]=v.x; a[i*4+1]=v.y; a[i*4+2]=v.z; a[i*4+3]=v.w; }
#pragma unroll
    for (int i = 0; i < 16; ++i) {
      float av = a[i];
#pragma unroll
      for (int j = 0; j < FF; ++j) m1[j] = fmaf(av, Wc[i * FF + j], m1[j]);
    }
  }
#pragma unroll
  for (int j = 0; j < FF; ++j) m1[j] = fmaxf(m1[j], 0.f);
  float m2[FF];
#pragma unroll
  for (int j = 0; j < FF; ++j) m2[j] = b2[j];
#pragma unroll
  for (int i = 0; i < FF; ++i) {
    float a = m1[i];
#pragma unroll
    for (int j = 0; j < FF; ++j) m2[j] = fmaf(a, W2[i * FF + j], m2[j]);
  }
  __hip_bfloat16* mrow = m + (size_t)t * FF * capSlots + sl;
#pragma unroll
  for (int j = 0; j < FF; ++j) mrow[(size_t)j * capSlots] = __float2bfloat16(m2[j]);
}

// ---------------- channel-parallel aggregation only (no LDS, no MLP) ----------------
// block = 320 threads = 16 nodes x 20 channels, one tower per block.
// Writes finalized agg stats fp32 to aggbuf[(n-n0)*4+t][80] = [mean|mn|mx|std]x20.
__global__ __launch_bounds__(320) void k_agg(
    const __hip_bfloat16* __restrict__ m,
    const int* __restrict__ row_ptr,
    const float* __restrict__ inv_deg,
    float* __restrict__ aggbuf, int n0, int n1, int capSlots) {
  int tid = threadIdx.x;
  int t = blockIdx.x & 3, tile = blockIdx.x >> 2;
  int ni = tid / FF, j = tid - ni * FF;
  int n = n0 + tile * 16 + ni;
  if (n >= n1) return;
  int base = row_ptr[n0];
  int beg = row_ptr[n], end = row_ptr[n + 1];
  float inv = inv_deg[n];
  int s0 = beg - base, s1c = end - base;
  if (s0 < 0) s0 = 0;
  if (s1c > capSlots) s1c = capSlots;
  float sum = 0.f, sq = 0.f, mnv = 3.4e38f, mxv = -3.4e38f;
  const unsigned short* mrow = (const unsigned short*)(m + (size_t)(t * FF + j) * capSlots);
  int p = s0;
  for (; p < s1c && (p & 3); ++p) {
    float v = __uint_as_float((unsigned)mrow[p] << 16);
    sum += v; sq += v * v; mnv = fminf(mnv, v); mxv = fmaxf(mxv, v);
  }
  for (; p + 4 <= s1c; p += 4) {
    ushort4 u = *(const ushort4*)(mrow + p);
    float v0 = __uint_as_float((unsigned)u.x << 16);
    float v1 = __uint_as_float((unsigned)u.y << 16);
    float v2 = __uint_as_float((unsigned)u.z << 16);
    float v3 = __uint_as_float((unsigned)u.w << 16);
    sum += (v0 + v1) + (v2 + v3);
    sq  += (v0 * v0 + v1 * v1) + (v2 * v2 + v3 * v3);
    mnv = fminf(mnv, fminf(fminf(v0, v1), fminf(v2, v3)));
    mxv = fmaxf(mxv, fmaxf(fmaxf(v0, v1), fmaxf(v2, v3)));
  }
  for (; p < s1c; ++p) {
    float v = __uint_as_float((unsigned)mrow[p] << 16);
    sum += v; sq += v * v; mnv = fminf(mnv, v); mxv = fmaxf(mxv, v);
  }
  float mu = sum * inv;
  float var = sq * inv - mu * mu;
  float sd = sqrtf(fmaxf(var, 0.f) + 1e-5f);
  if (end <= beg) { mnv = 0.f; mxv = 0.f; }
  float* ab = aggbuf + ((size_t)(n - n0) * 4 + t) * 80;
  ab[j]      = mu;
  ab[20 + j] = mnv;
  ab[40 + j] = mxv;
  ab[60 + j] = sd;
}

// ---------------- node-parallel post-MLP, SGPR weights (k_pre-style) ----------------
// block = 256 = 4 waves; wave = tower, lane = node. Weights wave-uniform ->
// scalar loads; inputs streamed (agg[i] loaded once, used for 3 scalings).
__global__ __launch_bounds__(256) void k_post2(
    const float* __restrict__ h, const float* __restrict__ aggbuf,
    const float* __restrict__ s1a, const float* __restrict__ s2a,
    const float* __restrict__ post_w1, const float* __restrict__ post_b1,
    const float* __restrict__ post_w2, const float* __restrict__ post_b2,
    float* __restrict__ out2, int l, int n0, int n1) {
  int tid = threadIdx.x;
  int t = tid >> 6, lane = tid & 63;
  int wt_u = __builtin_amdgcn_readfirstlane(l * TT + t);
  const float* Q1 = post_w1 + (size_t)wt_u * 5200;
  const float* Q2 = post_w2 + (size_t)wt_u * 400;
  const float* B1 = post_b1 + (size_t)wt_u * FF;
  const float* B2 = post_b2 + (size_t)wt_u * FF;
  int n = n0 + blockIdx.x * 64 + lane;
  if (n >= n1) return;
  float c1 = s1a[n], c2 = s2a[n];
  float o1[FF];
#pragma unroll
  for (int j = 0; j < FF; ++j) o1[j] = B1[j];
  const float* hrow = h + (size_t)n * DD + t * FF;
  for (int i = 0; i < FF; ++i) {
    float a = hrow[i];
#pragma unroll
    for (int j = 0; j < FF; ++j) o1[j] = fmaf(a, Q1[i * FF + j], o1[j]);
  }
  const float* ab = aggbuf + ((size_t)(n - n0) * 4 + t) * 80;
  for (int i = 0; i < 80; ++i) {
    float a0 = ab[i];
    float a1 = a0 * c1, a2 = a0 * c2;
    int r = FF + i;
#pragma unroll
    for (int j = 0; j < FF; ++j) o1[j] = fmaf(a0, Q1[r * FF + j], o1[j]);
#pragma unroll
    for (int j = 0; j < FF; ++j) o1[j] = fmaf(a1, Q1[(r + 80) * FF + j], o1[j]);
#pragma unroll
    for (int j = 0; j < FF; ++j) o1[j] = fmaf(a2, Q1[(r + 160) * FF + j], o1[j]);
  }
#pragma unroll
  for (int j = 0; j < FF; ++j) o1[j] = fmaxf(o1[j], 0.f);
  float o2[FF];
#pragma unroll
  for (int j = 0; j < FF; ++j) o2[j] = B2[j];
#pragma unroll
  for (int i = 0; i < FF; ++i) {
    float a = o1[i];
#pragma unroll
    for (int j = 0; j < FF; ++j) o2[j] = fmaf(a, Q2[i * FF + j], o2[j]);
  }
  float4* op = (float4*)(out2 + (size_t)n * DD + t * FF);
#pragma unroll
  for (int i = 0; i < 5; ++i) op[i] = make_float4(o2[i*4], o2[i*4+1], o2[i*4+2], o2[i*4+3]);
}

// ---------------- lin layer + BN column partial sums ----------------
__global__ __launch_bounds__(320) void k_lin(const float* __restrict__ out2,
                                             const float* __restrict__ lin_w,
                                             const float* __restrict__ lin_b,
                                             float* __restrict__ outl,
                                             float* __restrict__ colsum, int l) {
  __shared__ float Wl[DD * DD];
  __shared__ float rowbuf[4 * DD];
  __shared__ float red[320];
  int tid = threadIdx.x;
  for (int i = tid; i < DD * DD; i += 320) Wl[i] = lin_w[(size_t)l * DD * DD + i];
  __syncthreads();
  int nl = tid / DD, d = tid - nl * DD;
  float bias = lin_b[l * DD + d];
  float bsum = 0.f, bsq = 0.f;
  for (int base = blockIdx.x * 4; base < NN; base += gridDim.x * 4) {
    int gi = base * DD + tid;
    rowbuf[tid] = (gi < NN * DD) ? out2[gi] : 0.f;
    __syncthreads();
    int n = base + nl;
    if (n < NN) {
      float acc = bias;
#pragma unroll
      for (int i = 0; i < DD; ++i) acc = fmaf(rowbuf[nl * DD + i], Wl[i * DD + d], acc);
      outl[(size_t)n * DD + d] = acc;
      bsum += acc; bsq += acc * acc;
    }
    __syncthreads();
  }
  red[tid] = bsum;
  __syncthreads();
  if (tid < DD) {
    float s = red[tid] + red[tid + DD] + red[tid + 2 * DD] + red[tid + 3 * DD];
    atomicAdd(&colsum[d], s);
  }
  __syncthreads();
  red[tid] = bsq;
  __syncthreads();
  if (tid < DD) {
    float s = red[tid] + red[tid + DD] + red[tid + 2 * DD] + red[tid + 3 * DD];
    atomicAdd(&colsum[DD + d], s);
  }
}

// ---------------- BN finalize ----------------
__global__ __launch_bounds__(128) void k_bnfinal(const float* __restrict__ colsum,
                                                 const float* __restrict__ bn_g,
                                                 const float* __restrict__ bn_b,
                                                 float* __restrict__ bnsc, int l) {
  int d = threadIdx.x;
  if (d >= DD) return;
  float mu = colsum[d] * (1.0f / NN);
  float var = colsum[DD + d] * (1.0f / NN) - mu * mu;
  float sc = bn_g[l * DD + d] * rsqrtf(var + 1e-5f);
  bnsc[d] = sc;
  bnsc[DD + d] = bn_b[l * DD + d] - mu * sc;
}

// ---------------- BN apply + relu + residual into h ----------------
__global__ __launch_bounds__(256) void k_bnapply(const float* __restrict__ outl,
                                                 const float* __restrict__ bnsc,
                                                 float* __restrict__ h) {
  int idx = blockIdx.x * 256 + threadIdx.x;
  if (idx >= NN * DD) return;
  int d = idx % DD;
  float v = fmaf(outl[idx], bnsc[d], bnsc[DD + d]);
  h[idx] += fmaxf(v, 0.f);
}

// ---------------- graph pooling ----------------
__global__ __launch_bounds__(256) void k_gcnt(const int* __restrict__ batch, int* __restrict__ gcnt) {
  __shared__ int hcnt[GG];
  int tid = threadIdx.x;
  if (tid < GG) hcnt[tid] = 0;
  __syncthreads();
  int n = blockIdx.x * 256 + tid;
  if (n < NN) atomicAdd(&hcnt[batch[n]], 1);
  __syncthreads();
  if (tid < GG && hcnt[tid] > 0) atomicAdd(&gcnt[tid], hcnt[tid]);
}

__global__ void k_gstart(const int* __restrict__ gcnt, int* __restrict__ gstart) {
  if (threadIdx.x == 0 && blockIdx.x == 0) {
    int acc = 0;
    for (int g = 0; g < GG; ++g) { gstart[g] = acc; acc += gcnt[g]; }
  }
}

__global__ __launch_bounds__(320) void k_gmean(const float* __restrict__ h,
                                               const int* __restrict__ gstart,
                                               const int* __restrict__ gcnt,
                                               float* __restrict__ gbuf) {
  __shared__ float red[320];
  int g = blockIdx.x, tid = threadIdx.x;
  int nl = tid / DD, d = tid - nl * DD;
  int start = gstart[g], c = gcnt[g];
  float acc = 0.f;
  for (int r = start + nl; r < start + c; r += 4) acc += h[(size_t)r * DD + d];
  red[tid] = acc;
  __syncthreads();
  if (tid < DD) {
    float s = red[tid] + red[tid + DD] + red[tid + 2 * DD] + red[tid + 3 * DD];
    float cf = (c > 0) ? (float)c : 1.0f;
    gbuf[g * DD + tid] = s / cf;
  }
}

// ---------------- final MLP (tiny) ----------------
__global__ __launch_bounds__(64) void k_mlp(const float* __restrict__ gbuf,
                                            const float* __restrict__ w1, const float* __restrict__ b1,
                                            const float* __restrict__ w2, const float* __restrict__ b2,
                                            const float* __restrict__ w3, const float* __restrict__ b3,
                                            float* __restrict__ out) {
  __shared__ float row[DD];
  __shared__ float t1[40];
  __shared__ float t2[20];
  int g = blockIdx.x, tid = threadIdx.x;
  for (int i = tid; i < DD; i += 64) row[i] = gbuf[g * DD + i];
  __syncthreads();
  if (tid < 40) {
    float acc = b1[tid];
#pragma unroll
    for (int i = 0; i < DD; ++i) acc = fmaf(row[i], w1[i * 40 + tid], acc);
    t1[tid] = fmaxf(acc, 0.f);
  }
  __syncthreads();
  if (tid < 20) {
    float acc = b2[tid];
#pragma unroll
    for (int i = 0; i < 40; ++i) acc = fmaf(t1[i], w2[i * 20 + tid], acc);
    t2[tid] = fmaxf(acc, 0.f);
  }
  __syncthreads();
  if (tid == 0) {
    float acc = b3[0];
#pragma unroll
    for (int i = 0; i < 20; ++i) acc = fmaf(t2[i], w3[i], acc);
    out[g] = acc;
  }
}

extern "C" void kernel_launch(void* const* d_in, const int* in_sizes, int n_in,
                              void* d_out, int out_size, void* d_ws, size_t ws_size,
                              hipStream_t stream) {
  const int*   x         = (const int*)d_in[0];
  const int*   ei        = (const int*)d_in[1];
  const int*   batch     = (const int*)d_in[2];
  const float* edge_attr = (const float*)d_in[3];
  const float* atom_emb  = (const float*)d_in[4];
  const float* edge_w    = (const float*)d_in[5];
  const float* edge_b    = (const float*)d_in[6];
  const float* pre_w1    = (const float*)d_in[7];
  const float* pre_b1    = (const float*)d_in[8];
  const float* pre_w2    = (const float*)d_in[9];
  const float* pre_b2    = (const float*)d_in[10];
  const float* post_w1   = (const float*)d_in[11];
  const float* post_b1   = (const float*)d_in[12];
  const float* post_w2   = (const float*)d_in[13];
  const float* post_b2   = (const float*)d_in[14];
  const float* lin_w     = (const float*)d_in[15];
  const float* lin_b     = (const float*)d_in[16];
  const float* bn_g      = (const float*)d_in[17];
  const float* bn_b      = (const float*)d_in[18];
  const float* mlp_w1    = (const float*)d_in[19];
  const float* mlp_b1    = (const float*)d_in[20];
  const float* mlp_w2    = (const float*)d_in[21];
  const float* mlp_b2    = (const float*)d_in[22];
  const float* mlp_w3    = (const float*)d_in[23];
  const float* mlp_b3    = (const float*)d_in[24];
  float* out = (float*)d_out;

  // workspace carve-up — MUST stay within ws_size (R2 lesson)
  char* ws = (char*)d_ws;
  size_t off = 0;
  auto alloc = [&](size_t bytes) -> void* {
    void* p = ws + off;
    off += (bytes + 15) & ~(size_t)15;
    return p;
  };
  float* h       = (float*)alloc((size_t)NN * DD * 4);   // 16 MB
  float* out2    = (float*)alloc((size_t)NN * DD * 4);   // 16 MB (aliases predD)
  float* predS   = (float*)alloc((size_t)NN * DD * 4);   // 16 MB
  int2*  csr2    = (int2*)alloc((size_t)EE * 8);         // 6.4 MB
  int*   csr_dst = (int*)alloc((size_t)EE * 4);          // 3.2 MB
  int*   row_ptr = (int*)alloc((size_t)(NN + 1) * 4);
  int*   cnt     = (int*)alloc((size_t)NN * 4);
  int*   cursor  = (int*)alloc((size_t)NN * 4);
  float* inv_deg = (float*)alloc((size_t)NN * 4);
  float* s1a     = (float*)alloc((size_t)NN * 4);
  float* s2a     = (float*)alloc((size_t)NN * 4);
  float* colsum  = (float*)alloc(2 * DD * 4);
  float* bnsc    = (float*)alloc(2 * DD * 4);
  float* gbuf    = (float*)alloc((size_t)GG * DD * 4);
  float* wc      = (float*)alloc((size_t)TT * 16 * FF * 4);
  float* biasc   = (float*)alloc((size_t)TT * FF * 4);
  int*   bsum    = (int*)alloc((size_t)SCAN_B * 4);
  int*   boff    = (int*)alloc((size_t)SCAN_B * 4);
  int*   gcnt    = (int*)alloc((size_t)GG * 4);
  int*   gstart  = (int*)alloc((size_t)(GG + 1) * 4);
  float* predD   = out2; // alias: predD only ever read at dst rows of the current chunk
  (void)in_sizes; (void)n_in; (void)out_size;

  // remainder -> aggbuf (per-chunk fp32 stats) + bf16 m chunk buffer.
  // outl (16 MB, used by k_lin after m/agg are dead) aliases this region.
  size_t rest = (ws_size > off) ? (ws_size - off) : 0;
  static const int cands[] = {1, 2, 4, 5, 8, 10, 20, 25, 40, 50};
  int c = -1, capSlots = 0, nodesPer = 0;
  size_t aggBytes = 0;
  for (int ci = 0; ci < 10; ++ci) {
    int cc = cands[ci];
    int np = (NN + cc - 1) / cc;
    size_t ab = ((size_t)np * 4 * 80 * 4 + 63) & ~(size_t)63;
    int slots = EE / cc + 25000; if (slots > EE) slots = EE;
    slots = (slots + 63) & ~63;
    size_t mb = (size_t)slots * DD * 2;
    if (ab + mb <= rest && ab + mb >= (size_t)NN * DD * 4) {
      c = cc; capSlots = slots; nodesPer = np; aggBytes = ab;
      break;
    }
  }
  if (c < 0) { // degenerate fallback (should not trigger: ws >= 119 MB proven)
    c = 50; nodesPer = (NN + c - 1) / c;
    aggBytes = ((size_t)nodesPer * 4 * 80 * 4 + 63) & ~(size_t)63;
    size_t mb = (rest > aggBytes) ? rest - aggBytes : 0;
    capSlots = (int)(mb / (DD * 2)) & ~63;
  }
  float* aggbuf = (float*)(ws + off);
  __hip_bfloat16* mbuf = (__hip_bfloat16*)(ws + off + aggBytes);
  float* outl = aggbuf; // alias: k_lin runs after all chunks of the layer

  hipMemsetAsync(cnt, 0, (size_t)NN * 4, stream);
  k_h<<<(NN * DD + 255) / 256, 256, 0, stream>>>(x, atom_emb, h);
  k_deg<<<(EE + 255) / 256, 256, 0, stream>>>(ei, cnt);
  k_scan_sum<<<SCAN_B, 1024, 0, stream>>>(cnt, bsum);
  k_scan_top<<<1, 64, 0, stream>>>(bsum, boff, row_ptr);
  k_scan_apply<<<SCAN_B, 1024, 0, stream>>>(cnt, boff, row_ptr, cursor);
  k_csrfill<<<(EE + 255) / 256, 256, 0, stream>>>(ei, cursor, csr2, csr_dst);
  k_nodeparams<<<(NN + 255) / 256, 256, 0, stream>>>(cnt, inv_deg, s1a, s2a);

  for (int l = 0; l < LL; ++l) {
    k_wcomb<<<TT, 64, 0, stream>>>(edge_w, edge_b, pre_w1, pre_b1, wc, biasc, l);
    k_prenode<<<(NN + 63) / 64, 256, 0, stream>>>(h, pre_w1, biasc, predD, predS, l);
    for (int ck = 0; ck < c; ++ck) {
      int n0 = ck * nodesPer;
      int n1 = n0 + nodesPer; if (n1 > NN) n1 = NN;
      if (n0 >= n1) continue;
      int preBlocks = (capSlots + 63) / 64;
      k_pre<<<preBlocks, 256, 0, stream>>>(predD, predS, edge_attr, csr2, csr_dst, row_ptr,
          wc, pre_w2, pre_b2, mbuf, l, n0, n1, capSlots);
      int aggBlocks = ((n1 - n0 + 15) / 16) * 4;
      k_agg<<<aggBlocks, 320, 0, stream>>>(mbuf, row_ptr, inv_deg, aggbuf, n0, n1, capSlots);
      int p2Blocks = (n1 - n0 + 63) / 64;
      k_post2<<<p2Blocks, 256, 0, stream>>>(h, aggbuf, s1a, s2a,
          post_w1, post_b1, post_w2, post_b2, out2, l, n0, n1);
    }
    hipMemsetAsync(colsum, 0, 2 * DD * 4, stream);
    k_lin<<<512, 320, 0, stream>>>(out2, lin_w, lin_b, outl, colsum, l);
    k_bnfinal<<<1, 128, 0, stream>>>(colsum, bn_g, bn_b, bnsc, l);
    k_bnapply<<<(NN * DD + 255) / 256, 256, 0, stream>>>(outl, bnsc, h);
  }

  hipMemsetAsync(gcnt, 0, (size_t)GG * 4, stream);
  k_gcnt<<<(NN + 255) / 256, 256, 0, stream>>>(batch, gcnt);
  k_gstart<<<1, 64, 0, stream>>>(gcnt, gstart);
  k_gmean<<<GG, 320, 0, stream>>>(h, gstart, gcnt, gbuf);
  k_mlp<<<GG, 64, 0, stream>>>(gbuf, mlp_w1, mlp_b1, mlp_w2, mlp_b2, mlp_w3, mlp_b3, out);
}

// Round 10
// 1652.119 us; speedup vs baseline: 1.1065x; 1.1065x over previous
//
#include <hip/hip_runtime.h>
#include <hip/hip_bf16.h>

// Problem constants (from reference)
#define NN 50000
#define EE 800000
#define GG 128
#define LL 4
#define TT 4
#define FF 20
#define DD 80
#define SCAN_B ((NN + 1023) / 1024)   // 49
static constexpr float AVG_LOG = 2.8332133440562162f; // ln(17)

__device__ __forceinline__ float bf2f(unsigned short u) {
  return __uint_as_float((unsigned)u << 16);
}
__device__ __forceinline__ unsigned short f2bf(float f) {
  __hip_bfloat16 b = __float2bfloat16(f); // RNE
  return *(unsigned short*)&b;
}

// ---------------- h init: h[n,d] = sum_i atom_emb[i, x[n,i], d] ----------------
__global__ __launch_bounds__(256) void k_h(const int* __restrict__ x,
                                           const float* __restrict__ atom_emb,
                                           float* __restrict__ h) {
  int idx = blockIdx.x * 256 + threadIdx.x;
  if (idx >= NN * DD) return;
  int n = idx / DD, d = idx - n * DD;
  const int* xr = x + n * 9;
  float acc = 0.f;
#pragma unroll
  for (int i = 0; i < 9; ++i) {
    int v = xr[i];
    acc += atom_emb[(i * 16 + v) * DD + d];
  }
  h[idx] = acc;
}

// ---------------- degree count ----------------
__global__ __launch_bounds__(256) void k_deg(const int* __restrict__ ei, int* __restrict__ cnt) {
  int e = blockIdx.x * 256 + threadIdx.x;
  if (e >= EE) return;
  atomicAdd(&cnt[ei[EE + e]], 1); // dst = edge_index[1][e]
}

// ---------------- hierarchical exclusive scan ----------------
__global__ __launch_bounds__(1024) void k_scan_sum(const int* __restrict__ cnt, int* __restrict__ bsum) {
  __shared__ int red[1024];
  int tid = threadIdx.x;
  int i = blockIdx.x * 1024 + tid;
  red[tid] = (i < NN) ? cnt[i] : 0;
  __syncthreads();
  for (int off = 512; off > 0; off >>= 1) {
    if (tid < off) red[tid] += red[tid + off];
    __syncthreads();
  }
  if (tid == 0) bsum[blockIdx.x] = red[0];
}

__global__ void k_scan_top(const int* __restrict__ bsum, int* __restrict__ boff,
                           int* __restrict__ row_ptr) {
  if (threadIdx.x == 0 && blockIdx.x == 0) {
    int acc = 0;
    for (int b = 0; b < SCAN_B; ++b) { boff[b] = acc; acc += bsum[b]; }
    row_ptr[NN] = acc;
  }
}

__global__ __launch_bounds__(1024) void k_scan_apply(const int* __restrict__ cnt,
                                                     const int* __restrict__ boff,
                                                     int* __restrict__ row_ptr,
                                                     int* __restrict__ cursor) {
  __shared__ int sm[1024];
  int tid = threadIdx.x;
  int i = blockIdx.x * 1024 + tid;
  int v = (i < NN) ? cnt[i] : 0;
  sm[tid] = v;
  __syncthreads();
  for (int off = 1; off < 1024; off <<= 1) {
    int t = (tid >= off) ? sm[tid - off] : 0;
    __syncthreads();
    sm[tid] += t;
    __syncthreads();
  }
  int excl = boff[blockIdx.x] + sm[tid] - v;
  if (i < NN) { row_ptr[i] = excl; cursor[i] = excl; }
}

// ---------------- CSR fill: slot -> (src, edge) + dst ----------------
__global__ __launch_bounds__(256) void k_csrfill(const int* __restrict__ ei,
                                                 int* __restrict__ cursor,
                                                 int2* __restrict__ csr2,
                                                 int* __restrict__ csr_dst) {
  int e = blockIdx.x * 256 + threadIdx.x;
  if (e >= EE) return;
  int dst = ei[EE + e];
  int slot = atomicAdd(&cursor[dst], 1);
  csr2[slot] = make_int2(ei[e], e);
  csr_dst[slot] = dst;
}

// ---------------- per-node params ----------------
__global__ __launch_bounds__(256) void k_nodeparams(const int* __restrict__ cnt,
                                                    float* __restrict__ inv_deg,
                                                    float* __restrict__ s1a,
                                                    float* __restrict__ s2a) {
  int n = blockIdx.x * 256 + threadIdx.x;
  if (n >= NN) return;
  int c = cnt[n];
  float deg = (c > 0) ? (float)c : 1.0f;
  inv_deg[n] = 1.0f / deg;
  float logd = logf(deg + 1.0f);
  s1a[n] = logd / AVG_LOG;
  s2a[n] = AVG_LOG / logd;
}

// ---------------- per-layer weight composition ----------------
__global__ __launch_bounds__(64) void k_wcomb(const float* __restrict__ edge_w,
                                              const float* __restrict__ edge_b,
                                              const float* __restrict__ pre_w1,
                                              const float* __restrict__ pre_b1,
                                              float* __restrict__ wc,
                                              float* __restrict__ biasc, int l) {
  int t = blockIdx.x;
  int wt = l * TT + t;
  const float* W1 = pre_w1 + (size_t)wt * 1200; // [60][20]
  const float* ew = edge_w + (size_t)l * 16 * FF;
  const float* eb = edge_b + (size_t)l * FF;
  int j = threadIdx.x;
  if (j >= FF) return;
  for (int i = 0; i < 16; ++i) {
    float acc = 0.f;
#pragma unroll
    for (int f = 0; f < FF; ++f) acc = fmaf(ew[i * FF + f], W1[(40 + f) * FF + j], acc);
    wc[(t * 16 + i) * FF + j] = acc;
  }
  float b = pre_b1[wt * FF + j];
#pragma unroll
  for (int f = 0; f < FF; ++f) b = fmaf(eb[f], W1[(40 + f) * FF + j], b);
  biasc[t * FF + j] = b;
}

// ---------------- per-node pre contributions (bf16 out: halves gather bytes) ----------------
__global__ __launch_bounds__(256) void k_prenode(
    const float* __restrict__ h, const float* __restrict__ pre_w1,
    const float* __restrict__ biasc,
    unsigned short* __restrict__ predD, unsigned short* __restrict__ predS, int l) {
  int tid = threadIdx.x;
  int t = tid >> 6, lane = tid & 63;
  int n = blockIdx.x * 64 + lane;
  if (n >= NN) return;
  int wt_u = __builtin_amdgcn_readfirstlane(l * TT + t);
  const float* W1 = pre_w1 + (size_t)wt_u * 1200;
  const float* bc = biasc + t * FF;
  float xt[FF];
  {
    const float4* pp = (const float4*)(h + (size_t)n * DD + t * FF);
#pragma unroll
    for (int i = 0; i < 5; ++i) { float4 v = pp[i]; xt[i*4]=v.x; xt[i*4+1]=v.y; xt[i*4+2]=v.z; xt[i*4+3]=v.w; }
  }
  float d[FF], s[FF];
#pragma unroll
  for (int j = 0; j < FF; ++j) { d[j] = bc[j]; s[j] = 0.f; }
#pragma unroll
  for (int i = 0; i < FF; ++i) {
    float a = xt[i];
#pragma unroll
    for (int j = 0; j < FF; ++j) {
      d[j] = fmaf(a, W1[i * FF + j], d[j]);
      s[j] = fmaf(a, W1[(FF + i) * FF + j], s[j]);
    }
  }
  ushort4* pd = (ushort4*)(predD + (size_t)n * DD + t * FF);
  ushort4* ps = (ushort4*)(predS + (size_t)n * DD + t * FF);
#pragma unroll
  for (int i = 0; i < 5; ++i) {
    pd[i] = make_ushort4(f2bf(d[i*4]), f2bf(d[i*4+1]), f2bf(d[i*4+2]), f2bf(d[i*4+3]));
    ps[i] = make_ushort4(f2bf(s[i*4]), f2bf(s[i*4+1]), f2bf(s[i*4+2]), f2bf(s[i*4+3]));
  }
}

// ---------------- edge-parallel pre-MLP (reduced); m channel-major bf16 ----------------
__global__ __launch_bounds__(256, 4) void k_pre(
    const unsigned short* __restrict__ predD, const unsigned short* __restrict__ predS,
    const float* __restrict__ edge_attr,
    const int2* __restrict__ csr2, const int* __restrict__ csr_dst,
    const int* __restrict__ row_ptr,
    const float* __restrict__ wc,
    const float* __restrict__ pre_w2, const float* __restrict__ pre_b2,
    __hip_bfloat16* __restrict__ m, int l, int n0, int n1, int capSlots) {
  int tid = threadIdx.x;
  int t = tid >> 6;
  int lane = tid & 63;
  int wt_u = __builtin_amdgcn_readfirstlane(l * TT + t);
  int t_u  = __builtin_amdgcn_readfirstlane(t);
  const float* W2 = pre_w2 + (size_t)wt_u * 400;
  const float* b2 = pre_b2 + (size_t)wt_u * FF;
  const float* Wc = wc + (size_t)t_u * 16 * FF;

  int sl = blockIdx.x * 64 + lane;
  int base = row_ptr[n0], end = row_ptr[n1];
  if (sl >= capSlots || base + sl >= end) return;
  int p = base + sl;
  int2 se = csr2[p];
  int dst = csr_dst[p];

  float m1[FF];
  {
    const ushort4* pp = (const ushort4*)(predD + (size_t)dst * DD + t * FF);
    const ushort4* qq = (const ushort4*)(predS + (size_t)se.x * DD + t * FF);
#pragma unroll
    for (int i = 0; i < 5; ++i) {
      ushort4 u = pp[i];
      ushort4 v = qq[i];
      m1[i*4+0] = bf2f(u.x) + bf2f(v.x);
      m1[i*4+1] = bf2f(u.y) + bf2f(v.y);
      m1[i*4+2] = bf2f(u.z) + bf2f(v.z);
      m1[i*4+3] = bf2f(u.w) + bf2f(v.w);
    }
  }
  {
    float a[16];
    const float4* ap = (const float4*)(edge_attr + (size_t)se.y * 16);
#pragma unroll
    for (int i = 0; i < 4; ++i) { float4 v = ap[i]; a[i*4]=v.x; a[i*4+1]=v.y; a[i*4+2]=v.z; a[i*4+3]=v.w; }
#pragma unroll
    for (int i = 0; i < 16; ++i) {
      float av = a[i];
#pragma unroll
      for (int j = 0; j < FF; ++j) m1[j] = fmaf(av, Wc[i * FF + j], m1[j]);
    }
  }
#pragma unroll
  for (int j = 0; j < FF; ++j) m1[j] = fmaxf(m1[j], 0.f);
  float m2[FF];
#pragma unroll
  for (int j = 0; j < FF; ++j) m2[j] = b2[j];
#pragma unroll
  for (int i = 0; i < FF; ++i) {
    float a = m1[i];
#pragma unroll
    for (int j = 0; j < FF; ++j) m2[j] = fmaf(a, W2[i * FF + j], m2[j]);
  }
  __hip_bfloat16* mrow = m + (size_t)t * FF * capSlots + sl;
#pragma unroll
  for (int j = 0; j < FF; ++j) mrow[(size_t)j * capSlots] = __float2bfloat16(m2[j]);
}

// ---------------- channel-parallel aggregation (bf16 out) ----------------
// block = 320 threads = 16 nodes x 20 channels, one tower per block.
__global__ __launch_bounds__(320) void k_agg(
    const __hip_bfloat16* __restrict__ m,
    const int* __restrict__ row_ptr,
    const float* __restrict__ inv_deg,
    unsigned short* __restrict__ aggbuf, int n0, int n1, int capSlots) {
  int tid = threadIdx.x;
  int t = blockIdx.x & 3, tile = blockIdx.x >> 2;
  int ni = tid / FF, j = tid - ni * FF;
  int n = n0 + tile * 16 + ni;
  if (n >= n1) return;
  int base = row_ptr[n0];
  int beg = row_ptr[n], end = row_ptr[n + 1];
  float inv = inv_deg[n];
  int s0 = beg - base, s1c = end - base;
  if (s0 < 0) s0 = 0;
  if (s1c > capSlots) s1c = capSlots;
  float sum = 0.f, sq = 0.f, mnv = 3.4e38f, mxv = -3.4e38f;
  const unsigned short* mrow = (const unsigned short*)(m + (size_t)(t * FF + j) * capSlots);
  int p = s0;
  for (; p < s1c && (p & 3); ++p) {
    float v = bf2f(mrow[p]);
    sum += v; sq += v * v; mnv = fminf(mnv, v); mxv = fmaxf(mxv, v);
  }
  for (; p + 4 <= s1c; p += 4) {
    ushort4 u = *(const ushort4*)(mrow + p);
    float v0 = bf2f(u.x), v1 = bf2f(u.y), v2 = bf2f(u.z), v3 = bf2f(u.w);
    sum += (v0 + v1) + (v2 + v3);
    sq  += (v0 * v0 + v1 * v1) + (v2 * v2 + v3 * v3);
    mnv = fminf(mnv, fminf(fminf(v0, v1), fminf(v2, v3)));
    mxv = fmaxf(mxv, fmaxf(fmaxf(v0, v1), fmaxf(v2, v3)));
  }
  for (; p < s1c; ++p) {
    float v = bf2f(mrow[p]);
    sum += v; sq += v * v; mnv = fminf(mnv, v); mxv = fmaxf(mxv, v);
  }
  float mu = sum * inv;
  float var = sq * inv - mu * mu;
  float sd = sqrtf(fmaxf(var, 0.f) + 1e-5f);
  if (end <= beg) { mnv = 0.f; mxv = 0.f; }
  unsigned short* ab = aggbuf + ((size_t)(n - n0) * 4 + t) * 80;
  ab[j]      = f2bf(mu);
  ab[20 + j] = f2bf(mnv);
  ab[40 + j] = f2bf(mxv);
  ab[60 + j] = f2bf(sd);
}

// ---------------- node-parallel post-MLP, SGPR weights ----------------
__global__ __launch_bounds__(256) void k_post2(
    const float* __restrict__ h, const unsigned short* __restrict__ aggbuf,
    const float* __restrict__ s1a, const float* __restrict__ s2a,
    const float* __restrict__ post_w1, const float* __restrict__ post_b1,
    const float* __restrict__ post_w2, const float* __restrict__ post_b2,
    float* __restrict__ out2, int l, int n0, int n1) {
  int tid = threadIdx.x;
  int t = tid >> 6, lane = tid & 63;
  int wt_u = __builtin_amdgcn_readfirstlane(l * TT + t);
  const float* Q1 = post_w1 + (size_t)wt_u * 5200;
  const float* Q2 = post_w2 + (size_t)wt_u * 400;
  const float* B1 = post_b1 + (size_t)wt_u * FF;
  const float* B2 = post_b2 + (size_t)wt_u * FF;
  int n = n0 + blockIdx.x * 64 + lane;
  if (n >= n1) return;
  float c1 = s1a[n], c2 = s2a[n];
  float o1[FF];
#pragma unroll
  for (int j = 0; j < FF; ++j) o1[j] = B1[j];
  const float* hrow = h + (size_t)n * DD + t * FF;
  for (int i = 0; i < FF; ++i) {
    float a = hrow[i];
#pragma unroll
    for (int j = 0; j < FF; ++j) o1[j] = fmaf(a, Q1[i * FF + j], o1[j]);
  }
  const unsigned short* ab = aggbuf + ((size_t)(n - n0) * 4 + t) * 80;
  for (int i = 0; i < 80; ++i) {
    float a0 = bf2f(ab[i]);
    float a1 = a0 * c1, a2 = a0 * c2;
    int r = FF + i;
#pragma unroll
    for (int j = 0; j < FF; ++j) o1[j] = fmaf(a0, Q1[r * FF + j], o1[j]);
#pragma unroll
    for (int j = 0; j < FF; ++j) o1[j] = fmaf(a1, Q1[(r + 80) * FF + j], o1[j]);
#pragma unroll
    for (int j = 0; j < FF; ++j) o1[j] = fmaf(a2, Q1[(r + 160) * FF + j], o1[j]);
  }
#pragma unroll
  for (int j = 0; j < FF; ++j) o1[j] = fmaxf(o1[j], 0.f);
  float o2[FF];
#pragma unroll
  for (int j = 0; j < FF; ++j) o2[j] = B2[j];
#pragma unroll
  for (int i = 0; i < FF; ++i) {
    float a = o1[i];
#pragma unroll
    for (int j = 0; j < FF; ++j) o2[j] = fmaf(a, Q2[i * FF + j], o2[j]);
  }
  float4* op = (float4*)(out2 + (size_t)n * DD + t * FF);
#pragma unroll
  for (int i = 0; i < 5; ++i) op[i] = make_float4(o2[i*4], o2[i*4+1], o2[i*4+2], o2[i*4+3]);
}

// ---------------- lin layer + BN column partial sums ----------------
__global__ __launch_bounds__(320) void k_lin(const float* __restrict__ out2,
                                             const float* __restrict__ lin_w,
                                             const float* __restrict__ lin_b,
                                             float* __restrict__ outl,
                                             float* __restrict__ colsum, int l) {
  __shared__ float Wl[DD * DD];
  __shared__ float rowbuf[4 * DD];
  __shared__ float red[320];
  int tid = threadIdx.x;
  for (int i = tid; i < DD * DD; i += 320) Wl[i] = lin_w[(size_t)l * DD * DD + i];
  __syncthreads();
  int nl = tid / DD, d = tid - nl * DD;
  float bias = lin_b[l * DD + d];
  float bsum = 0.f, bsq = 0.f;
  for (int base = blockIdx.x * 4; base < NN; base += gridDim.x * 4) {
    int gi = base * DD + tid;
    rowbuf[tid] = (gi < NN * DD) ? out2[gi] : 0.f;
    __syncthreads();
    int n = base + nl;
    if (n < NN) {
      float acc = bias;
#pragma unroll
      for (int i = 0; i < DD; ++i) acc = fmaf(rowbuf[nl * DD + i], Wl[i * DD + d], acc);
      outl[(size_t)n * DD + d] = acc;
      bsum += acc; bsq += acc * acc;
    }
    __syncthreads();
  }
  red[tid] = bsum;
  __syncthreads();
  if (tid < DD) {
    float s = red[tid] + red[tid + DD] + red[tid + 2 * DD] + red[tid + 3 * DD];
    atomicAdd(&colsum[d], s);
  }
  __syncthreads();
  red[tid] = bsq;
  __syncthreads();
  if (tid < DD) {
    float s = red[tid] + red[tid + DD] + red[tid + 2 * DD] + red[tid + 3 * DD];
    atomicAdd(&colsum[DD + d], s);
  }
}

// ---------------- BN finalize ----------------
__global__ __launch_bounds__(128) void k_bnfinal(const float* __restrict__ colsum,
                                                 const float* __restrict__ bn_g,
                                                 const float* __restrict__ bn_b,
                                                 float* __restrict__ bnsc, int l) {
  int d = threadIdx.x;
  if (d >= DD) return;
  float mu = colsum[d] * (1.0f / NN);
  float var = colsum[DD + d] * (1.0f / NN) - mu * mu;
  float sc = bn_g[l * DD + d] * rsqrtf(var + 1e-5f);
  bnsc[d] = sc;
  bnsc[DD + d] = bn_b[l * DD + d] - mu * sc;
}

// ---------------- BN apply + relu + residual into h ----------------
__global__ __launch_bounds__(256) void k_bnapply(const float* __restrict__ outl,
                                                 const float* __restrict__ bnsc,
                                                 float* __restrict__ h) {
  int idx = blockIdx.x * 256 + threadIdx.x;
  if (idx >= NN * DD) return;
  int d = idx % DD;
  float v = fmaf(outl[idx], bnsc[d], bnsc[DD + d]);
  h[idx] += fmaxf(v, 0.f);
}

// ---------------- graph pooling ----------------
__global__ __launch_bounds__(256) void k_gcnt(const int* __restrict__ batch, int* __restrict__ gcnt) {
  __shared__ int hcnt[GG];
  int tid = threadIdx.x;
  if (tid < GG) hcnt[tid] = 0;
  __syncthreads();
  int n = blockIdx.x * 256 + tid;
  if (n < NN) atomicAdd(&hcnt[batch[n]], 1);
  __syncthreads();
  if (tid < GG && hcnt[tid] > 0) atomicAdd(&gcnt[tid], hcnt[tid]);
}

__global__ void k_gstart(const int* __restrict__ gcnt, int* __restrict__ gstart) {
  if (threadIdx.x == 0 && blockIdx.x == 0) {
    int acc = 0;
    for (int g = 0; g < GG; ++g) { gstart[g] = acc; acc += gcnt[g]; }
  }
}

__global__ __launch_bounds__(320) void k_gmean(const float* __restrict__ h,
                                               const int* __restrict__ gstart,
                                               const int* __restrict__ gcnt,
                                               float* __restrict__ gbuf) {
  __shared__ float red[320];
  int g = blockIdx.x, tid = threadIdx.x;
  int nl = tid / DD, d = tid - nl * DD;
  int start = gstart[g], c = gcnt[g];
  float acc = 0.f;
  for (int r = start + nl; r < start + c; r += 4) acc += h[(size_t)r * DD + d];
  red[tid] = acc;
  __syncthreads();
  if (tid < DD) {
    float s = red[tid] + red[tid + DD] + red[tid + 2 * DD] + red[tid + 3 * DD];
    float cf = (c > 0) ? (float)c : 1.0f;
    gbuf[g * DD + tid] = s / cf;
  }
}

// ---------------- final MLP (tiny) ----------------
__global__ __launch_bounds__(64) void k_mlp(const float* __restrict__ gbuf,
                                            const float* __restrict__ w1, const float* __restrict__ b1,
                                            const float* __restrict__ w2, const float* __restrict__ b2,
                                            const float* __restrict__ w3, const float* __restrict__ b3,
                                            float* __restrict__ out) {
  __shared__ float row[DD];
  __shared__ float t1[40];
  __shared__ float t2[20];
  int g = blockIdx.x, tid = threadIdx.x;
  for (int i = tid; i < DD; i += 64) row[i] = gbuf[g * DD + i];
  __syncthreads();
  if (tid < 40) {
    float acc = b1[tid];
#pragma unroll
    for (int i = 0; i < DD; ++i) acc = fmaf(row[i], w1[i * 40 + tid], acc);
    t1[tid] = fmaxf(acc, 0.f);
  }
  __syncthreads();
  if (tid < 20) {
    float acc = b2[tid];
#pragma unroll
    for (int i = 0; i < 40; ++i) acc = fmaf(t1[i], w2[i * 20 + tid], acc);
    t2[tid] = fmaxf(acc, 0.f);
  }
  __syncthreads();
  if (tid == 0) {
    float acc = b3[0];
#pragma unroll
    for (int i = 0; i < 20; ++i) acc = fmaf(t2[i], w3[i], acc);
    out[g] = acc;
  }
}

extern "C" void kernel_launch(void* const* d_in, const int* in_sizes, int n_in,
                              void* d_out, int out_size, void* d_ws, size_t ws_size,
                              hipStream_t stream) {
  const int*   x         = (const int*)d_in[0];
  const int*   ei        = (const int*)d_in[1];
  const int*   batch     = (const int*)d_in[2];
  const float* edge_attr = (const float*)d_in[3];
  const float* atom_emb  = (const float*)d_in[4];
  const float* edge_w    = (const float*)d_in[5];
  const float* edge_b    = (const float*)d_in[6];
  const float* pre_w1    = (const float*)d_in[7];
  const float* pre_b1    = (const float*)d_in[8];
  const float* pre_w2    = (const float*)d_in[9];
  const float* pre_b2    = (const float*)d_in[10];
  const float* post_w1   = (const float*)d_in[11];
  const float* post_b1   = (const float*)d_in[12];
  const float* post_w2   = (const float*)d_in[13];
  const float* post_b2   = (const float*)d_in[14];
  const float* lin_w     = (const float*)d_in[15];
  const float* lin_b     = (const float*)d_in[16];
  const float* bn_g      = (const float*)d_in[17];
  const float* bn_b      = (const float*)d_in[18];
  const float* mlp_w1    = (const float*)d_in[19];
  const float* mlp_b1    = (const float*)d_in[20];
  const float* mlp_w2    = (const float*)d_in[21];
  const float* mlp_b2    = (const float*)d_in[22];
  const float* mlp_w3    = (const float*)d_in[23];
  const float* mlp_b3    = (const float*)d_in[24];
  float* out = (float*)d_out;

  // workspace carve-up — MUST stay within ws_size (R2 lesson)
  char* ws = (char*)d_ws;
  size_t off = 0;
  auto alloc = [&](size_t bytes) -> void* {
    void* p = ws + off;
    off += (bytes + 15) & ~(size_t)15;
    return p;
  };
  float* h       = (float*)alloc((size_t)NN * DD * 4);           // 16 MB
  float* out2    = (float*)alloc((size_t)NN * DD * 4);           // 16 MB
  unsigned short* predD = (unsigned short*)alloc((size_t)NN * DD * 2); // 8 MB bf16
  unsigned short* predS = (unsigned short*)alloc((size_t)NN * DD * 2); // 8 MB bf16
  int2*  csr2    = (int2*)alloc((size_t)EE * 8);                 // 6.4 MB
  int*   csr_dst = (int*)alloc((size_t)EE * 4);                  // 3.2 MB
  int*   row_ptr = (int*)alloc((size_t)(NN + 1) * 4);
  int*   cnt     = (int*)alloc((size_t)NN * 4);
  int*   cursor  = (int*)alloc((size_t)NN * 4);
  float* inv_deg = (float*)alloc((size_t)NN * 4);
  float* s1a     = (float*)alloc((size_t)NN * 4);
  float* s2a     = (float*)alloc((size_t)NN * 4);
  float* colsum  = (float*)alloc(2 * DD * 4);
  float* bnsc    = (float*)alloc(2 * DD * 4);
  float* gbuf    = (float*)alloc((size_t)GG * DD * 4);
  float* wc      = (float*)alloc((size_t)TT * 16 * FF * 4);
  float* biasc   = (float*)alloc((size_t)TT * FF * 4);
  int*   bsum    = (int*)alloc((size_t)SCAN_B * 4);
  int*   boff    = (int*)alloc((size_t)SCAN_B * 4);
  int*   gcnt    = (int*)alloc((size_t)GG * 4);
  int*   gstart  = (int*)alloc((size_t)(GG + 1) * 4);
  (void)in_sizes; (void)n_in; (void)out_size;

  // remainder -> aggbuf (bf16 stats) + bf16 m chunk buffer; outl aliases region.
  size_t rest = (ws_size > off) ? (ws_size - off) : 0;
  static const int cands[] = {1, 2, 4, 5, 8, 10, 20, 25, 40, 50};
  int c = -1, capSlots = 0, nodesPer = 0;
  size_t aggBytes = 0;
  for (int ci = 0; ci < 10; ++ci) {
    int cc = cands[ci];
    int np = (NN + cc - 1) / cc;
    size_t ab = ((size_t)np * 4 * 80 * 2 + 63) & ~(size_t)63;    // bf16 stats
    int slots = EE / cc + 25000; if (slots > EE) slots = EE;
    slots = (slots + 63) & ~63;
    size_t mb = (size_t)slots * DD * 2;
    if (ab + mb <= rest && ab + mb >= (size_t)NN * DD * 4) {     // outl (16 MB) must fit alias
      c = cc; capSlots = slots; nodesPer = np; aggBytes = ab;
      break;
    }
  }
  if (c < 0) { // degenerate fallback
    c = 50; nodesPer = (NN + c - 1) / c;
    aggBytes = ((size_t)nodesPer * 4 * 80 * 2 + 63) & ~(size_t)63;
    size_t mb = (rest > aggBytes) ? rest - aggBytes : 0;
    capSlots = (int)(mb / (DD * 2)) & ~63;
  }
  unsigned short* aggbuf = (unsigned short*)(ws + off);
  __hip_bfloat16* mbuf = (__hip_bfloat16*)(ws + off + aggBytes);
  float* outl = (float*)(ws + off); // alias: k_lin runs after all chunks of the layer

  hipMemsetAsync(cnt, 0, (size_t)NN * 4, stream);
  k_h<<<(NN * DD + 255) / 256, 256, 0, stream>>>(x, atom_emb, h);
  k_deg<<<(EE + 255) / 256, 256, 0, stream>>>(ei, cnt);
  k_scan_sum<<<SCAN_B, 1024, 0, stream>>>(cnt, bsum);
  k_scan_top<<<1, 64, 0, stream>>>(bsum, boff, row_ptr);
  k_scan_apply<<<SCAN_B, 1024, 0, stream>>>(cnt, boff, row_ptr, cursor);
  k_csrfill<<<(EE + 255) / 256, 256, 0, stream>>>(ei, cursor, csr2, csr_dst);
  k_nodeparams<<<(NN + 255) / 256, 256, 0, stream>>>(cnt, inv_deg, s1a, s2a);

  for (int l = 0; l < LL; ++l) {
    k_wcomb<<<TT, 64, 0, stream>>>(edge_w, edge_b, pre_w1, pre_b1, wc, biasc, l);
    k_prenode<<<(NN + 63) / 64, 256, 0, stream>>>(h, pre_w1, biasc, predD, predS, l);
    for (int ck = 0; ck < c; ++ck) {
      int n0 = ck * nodesPer;
      int n1 = n0 + nodesPer; if (n1 > NN) n1 = NN;
      if (n0 >= n1) continue;
      int preBlocks = (capSlots + 63) / 64;
      k_pre<<<preBlocks, 256, 0, stream>>>(predD, predS, edge_attr, csr2, csr_dst, row_ptr,
          wc, pre_w2, pre_b2, mbuf, l, n0, n1, capSlots);
      int aggBlocks = ((n1 - n0 + 15) / 16) * 4;
      k_agg<<<aggBlocks, 320, 0, stream>>>(mbuf, row_ptr, inv_deg, aggbuf, n0, n1, capSlots);
      int p2Blocks = (n1 - n0 + 63) / 64;
      k_post2<<<p2Blocks, 256, 0, stream>>>(h, aggbuf, s1a, s2a,
          post_w1, post_b1, post_w2, post_b2, out2, l, n0, n1);
    }
    hipMemsetAsync(colsum, 0, 2 * DD * 4, stream);
    k_lin<<<512, 320, 0, stream>>>(out2, lin_w, lin_b, outl, colsum, l);
    k_bnfinal<<<1, 128, 0, stream>>>(colsum, bn_g, bn_b, bnsc, l);
    k_bnapply<<<(NN * DD + 255) / 256, 256, 0, stream>>>(outl, bnsc, h);
  }

  hipMemsetAsync(gcnt, 0, (size_t)GG * 4, stream);
  k_gcnt<<<(NN + 255) / 256, 256, 0, stream>>>(batch, gcnt);
  k_gstart<<<1, 64, 0, stream>>>(gcnt, gstart);
  k_gmean<<<GG, 320, 0, stream>>>(h, gstart, gcnt, gbuf);
  k_mlp<<<GG, 64, 0, stream>>>(gbuf, mlp_w1, mlp_b1, mlp_w2, mlp_b2, mlp_w3, mlp_b3, out);
}